// Round 1
// 286.255 us; speedup vs baseline: 1.1534x; 1.1534x over previous
//
#include <hip/hip_runtime.h>
#include <hip/hip_bf16.h>

typedef __bf16 bf16_t;
typedef __bf16 bf16x4 __attribute__((ext_vector_type(4)));
typedef __bf16 bf16x8 __attribute__((ext_vector_type(8)));
typedef float f32x4 __attribute__((ext_vector_type(4)));

#define MFMA16(a, b, c) __builtin_amdgcn_mfma_f32_16x16x32_bf16(a, b, c, 0, 0, 0)

// async 16B global->LDS (m97 pattern). lds ptr wave-uniform; lane writes
// ldsbase + lane*16.
__device__ __forceinline__ void gld16(const bf16_t* g, bf16_t* l) {
  __builtin_amdgcn_global_load_lds(
      (const __attribute__((address_space(1))) unsigned int*)(const void*)g,
      (__attribute__((address_space(3))) unsigned int*)(void*)l, 16, 0, 0);
}

// ---------------------------------------------------------------------------
// f32 -> bf16 elementwise convert (n multiple of 8)
// ---------------------------------------------------------------------------
__global__ __launch_bounds__(256) void cvt_f32_bf16(
    const float* __restrict__ src, bf16_t* __restrict__ dst, long long n) {
  long long i = ((long long)blockIdx.x * 256 + threadIdx.x) * 8;
  const long long stride = (long long)gridDim.x * 256 * 8;
  for (; i < n; i += stride) {
    f32x4 a = *(const f32x4*)(src + i);
    f32x4 b = *(const f32x4*)(src + i + 4);
    bf16x8 r;
#pragma unroll
    for (int e = 0; e < 4; ++e) {
      r[e] = (bf16_t)a[e];
      r[4 + e] = (bf16_t)b[e];
    }
    *(bf16x8*)(dst + i) = r;
  }
}

// ---------------------------------------------------------------------------
// GEMM: C[m][n] = sum_k A[m][k]*W[n][k] (+bias). A bf16 via global_load_lds.
// W: bf16 via global_load_lds (WF32=false) or f32 via cvt staging (true).
// 128x128 tile, 4 waves (2x2), 64x64/wave, BK=32. Layouts R5==R6 verified.
// ---------------------------------------------------------------------------
template <bool WF32, typename TC, bool BIAS>
__global__ __launch_bounds__(256, 2) void gemm_async(
    const bf16_t* __restrict__ A, int lda, const void* __restrict__ Wv,
    const float* __restrict__ bias, TC* __restrict__ C, int ldc,
    int M, int N, int K) {
  constexpr int BST = WF32 ? 40 : 32;
  __shared__ bf16_t As[128 * 32];   // unpadded: global_load_lds layout
  __shared__ bf16_t Bs[128 * BST];

  const int tid = threadIdx.x;
  const int i = tid & 63;
  const int w = tid >> 6;
  const int l16 = tid & 15;
  const int quad = (tid >> 4) & 3;
  const int wm = w & 1;
  const int wn = w >> 1;
  const int m0 = blockIdx.y * 128;
  const int n0 = blockIdx.x * 128;

  const bf16_t* ag = A + (size_t)(m0 + w * 32 + (i >> 2)) * lda + (i & 3) * 8;
  bf16_t* as0 = &As[(w * 32) * 32];
  bf16_t* as1 = &As[(w * 32 + 16) * 32];

  const bf16_t* bg = nullptr;
  bf16_t *bs0 = nullptr, *bs1 = nullptr;
  const float* wfg = nullptr;
  bf16_t* bsw = nullptr;
  if (!WF32) {
    bg = (const bf16_t*)Wv + (size_t)(n0 + w * 32 + (i >> 2)) * K + (i & 3) * 8;
    bs0 = &Bs[(w * 32) * 32];
    bs1 = &Bs[(w * 32 + 16) * 32];
  } else {
    const int srow = tid >> 1;
    const int scol = (tid & 1) * 16;
    wfg = (const float*)Wv + (size_t)(n0 + srow) * K + scol;
    bsw = &Bs[srow * BST + scol];
  }

  f32x4 acc[4][4] = {};

  for (int k0 = 0; k0 < K; k0 += 32) {
    __syncthreads();
    gld16(ag + k0, as0);
    gld16(ag + 16 * lda + k0, as1);
    if (!WF32) {
      gld16(bg + k0, bs0);
      gld16(bg + 16 * K + k0, bs1);
    } else {
      f32x4 a = *(const f32x4*)(wfg + k0);
      f32x4 b = *(const f32x4*)(wfg + k0 + 4);
      f32x4 c2 = *(const f32x4*)(wfg + k0 + 8);
      f32x4 d = *(const f32x4*)(wfg + k0 + 12);
      bf16x8 r0, r1;
#pragma unroll
      for (int e = 0; e < 4; ++e) {
        r0[e] = (bf16_t)a[e];
        r0[4 + e] = (bf16_t)b[e];
        r1[e] = (bf16_t)c2[e];
        r1[4 + e] = (bf16_t)d[e];
      }
      *(bf16x8*)(bsw) = r0;
      *(bf16x8*)(bsw + 8) = r1;
    }
    __syncthreads();

    bf16x8 af[4], bfr[4];
#pragma unroll
    for (int t = 0; t < 4; ++t) {
      af[t] = *(const bf16x8*)&As[(wm * 64 + t * 16 + l16) * 32 + quad * 8];
      bfr[t] = *(const bf16x8*)&Bs[(wn * 64 + t * 16 + l16) * BST + quad * 8];
    }
#pragma unroll
    for (int mi = 0; mi < 4; ++mi)
#pragma unroll
      for (int ni = 0; ni < 4; ++ni)
        acc[mi][ni] = MFMA16(af[mi], bfr[ni], acc[mi][ni]);
  }

#pragma unroll
  for (int ni = 0; ni < 4; ++ni) {
    const int col = n0 + wn * 64 + ni * 16 + l16;
    const float bv = BIAS ? bias[col] : 0.0f;
#pragma unroll
    for (int mi = 0; mi < 4; ++mi) {
      const int row = m0 + wm * 64 + mi * 16 + quad * 4;
#pragma unroll
      for (int r = 0; r < 4; ++r)
        C[(size_t)(row + r) * ldc + col] = (TC)(acc[mi][ni][r] + bv);
    }
  }
}

// ---------------------------------------------------------------------------
// Flash attention (causal), qkv interleaved [B*T, 3C] bf16 (q|k|v).
// Output overwrites the Q slot in place (R3-verified disjointness).
//
// Work-balanced: block p processes q-strips qt=p and qt=15-p -> every block
// does exactly 34 j-tiles. Grid (8, B*H) = 512 blocks of 512 threads.
//
// v2 (this round): SWAPPED QK^T — S^T = mfma(K_frag, Q_frag). A-frag and
// B-frag share the same lane->(idx,k) mapping, so swapping operand roles is
// an exact transpose: lane now holds S[qlo+l16][j0 + nt*16 + quad*4 + r].
//  * row max/sum: in-lane over 16 vals + 2 shfl_xor(16,32) each
//    (was 8 shuffles x 4 rows = 32/tile -> now ~10/tile incl. broadcasts)
//  * mrow/lrow scalars; 1 alpha exp/tile (was 4)
//  * P staging: lane's 4 r-values are 4 CONSECUTIVE keys -> 4x ds_write_b64
//    (was 16x ds_write_b16 with 4-way quad conflicts). Read path unchanged.
//  * exact defer-skip: rescale block skipped when no row max grew
//    (alpha==1 exactly) — bit-identical numerics.
//  * async-STAGE split (T14): next tile's K/V global->reg loads issued right
//    after the LDS commit; latency hides under QK^T/softmax/PV.
//  * s_setprio(1) around MFMA clusters (T5).
// ---------------------------------------------------------------------------
__global__ __launch_bounds__(512, 4) void attn_mfma(bf16_t* __restrict__ qkv) {
  constexpr int T = 2048, C3 = 3072, C = 1024;
  __shared__ bf16_t Ks[64 * 72];      // [token][d], +8 pad
  __shared__ bf16_t Vt[64 * 72];      // [d][token], +8 pad
  __shared__ bf16_t Ps[8 * 16 * 72];  // per-wave P tile [qrow][key]

  const int tid = threadIdx.x;
  const int wave = tid >> 6;        // 0..7
  const int lane = tid & 63;
  const int l16 = tid & 15;
  const int quad = (tid >> 4) & 3;
  const int p = blockIdx.x;         // 0..7 -> strips p and 15-p
  const int b = blockIdx.y >> 4;
  const int h = blockIdx.y & 15;
  bf16_t* base = qkv + (size_t)b * T * C3;

  // K staging map (waves 0-3): token = tid>>2 (0..63), 16 d's at (tid&3)*16
  const int kst = tid >> 2;
  const int ksd = (tid & 3) * 16;
  // V staging map (waves 4-7): token = lane, 16 d's at (wave-4)*16
  const int vtok = lane;
  const int vdg = (wave - 4) * 16;

  bf16_t* pw = &Ps[wave * 16 * 72];

  bf16x8 st0, st1;  // staging regs: K halves (waves 0-3) or V halves (4-7)

  for (int s = 0; s < 2; ++s) {
    const int qt = (s == 0) ? p : 15 - p;
    const int Q0 = qt * 128;
    const int qlo = Q0 + wave * 16;
    const int jmax = Q0 + 64;

    // Q fragments, prescaled by 0.125 (power of 2: exact in bf16)
    bf16x8 qf[2];
    {
      const bf16_t* qp = base + (size_t)(qlo + l16) * C3 + h * 64 + quad * 8;
      bf16x8 a = *(const bf16x8*)qp;
      bf16x8 c = *(const bf16x8*)(qp + 32);
#pragma unroll
      for (int e = 0; e < 8; ++e) {
        a[e] = (bf16_t)((float)a[e] * 0.125f);
        c[e] = (bf16_t)((float)c[e] * 0.125f);
      }
      qf[0] = a;
      qf[1] = c;
    }

    f32x4 Of[4] = {};
    float mrow = -1e30f;
    float lrow = 0.f;

    // prologue: issue tile-0 loads into regs (T14 split)
    if (wave < 4) {
      const bf16_t* kp = base + (size_t)kst * C3 + C + h * 64 + ksd;
      st0 = *(const bf16x8*)kp;
      st1 = *(const bf16x8*)(kp + 8);
    } else {
      const bf16_t* vp = base + (size_t)vtok * C3 + 2 * C + h * 64 + vdg;
      st0 = *(const bf16x8*)vp;
      st1 = *(const bf16x8*)(vp + 8);
    }

    for (int j0 = 0; j0 <= jmax; j0 += 64) {
      __syncthreads();  // previous tile's Ks/Vt readers are done
      // commit staged regs -> LDS (implicit vmcnt wait on st0/st1)
      if (wave < 4) {
        *(bf16x8*)&Ks[kst * 72 + ksd] = st0;
        *(bf16x8*)&Ks[kst * 72 + ksd + 8] = st1;
      } else {
#pragma unroll
        for (int e = 0; e < 8; ++e) {
          Vt[(vdg + e) * 72 + vtok] = st0[e];
          Vt[(vdg + 8 + e) * 72 + vtok] = st1[e];
        }
      }
      // issue next tile's loads; latency hides under compute below
      if (j0 + 64 <= jmax) {
        const int jn = j0 + 64;
        if (wave < 4) {
          const bf16_t* kp = base + (size_t)(jn + kst) * C3 + C + h * 64 + ksd;
          st0 = *(const bf16x8*)kp;
          st1 = *(const bf16x8*)(kp + 8);
        } else {
          const bf16_t* vp =
              base + (size_t)(jn + vtok) * C3 + 2 * C + h * 64 + vdg;
          st0 = *(const bf16x8*)vp;
          st1 = *(const bf16x8*)(vp + 8);
        }
      }
      __syncthreads();

      if (qlo + 15 < j0) continue;  // wave-uniform: fully-masked wave skips

      // S^T tile: lane holds S[qlo+l16][j0 + nt*16 + quad*4 + r]
      float Sv[4][4];
      const int qrow = qlo + l16;
      __builtin_amdgcn_s_setprio(1);
#pragma unroll
      for (int nt = 0; nt < 4; ++nt) {
        f32x4 sacc = {};
#pragma unroll
        for (int s2 = 0; s2 < 2; ++s2) {
          bf16x8 kf =
              *(const bf16x8*)&Ks[(nt * 16 + l16) * 72 + s2 * 32 + quad * 8];
          sacc = MFMA16(kf, qf[s2], sacc);  // swapped: rows=keys, cols=qrows
        }
        const int keyb = j0 + nt * 16 + quad * 4;
#pragma unroll
        for (int r = 0; r < 4; ++r)
          Sv[nt][r] = (keyb + r > qrow) ? -1e30f : sacc[r];
      }
      __builtin_amdgcn_s_setprio(0);

      // tile max for this lane's row (tree, then cross-quad)
      float vm[4];
#pragma unroll
      for (int nt = 0; nt < 4; ++nt)
        vm[nt] = fmaxf(fmaxf(Sv[nt][0], Sv[nt][1]),
                       fmaxf(Sv[nt][2], Sv[nt][3]));
      float v = fmaxf(fmaxf(vm[0], vm[1]), fmaxf(vm[2], vm[3]));
      v = fmaxf(v, __shfl_xor(v, 16));
      v = fmaxf(v, __shfl_xor(v, 32));

      // exact defer-skip: when no row grew, alpha==1 exactly -> skip rescale
      if (__any(v > mrow)) {
        const float mnew = fmaxf(mrow, v);
        const float alpha = __expf(mrow - mnew);
        mrow = mnew;
        lrow *= alpha;
        float ar[4];
#pragma unroll
        for (int r = 0; r < 4; ++r) ar[r] = __shfl(alpha, quad * 4 + r, 16);
#pragma unroll
        for (int dt = 0; dt < 4; ++dt)
#pragma unroll
          for (int r = 0; r < 4; ++r) Of[dt][r] *= ar[r];
      }

      // P = exp(S - m); pack 4 consecutive keys -> one ds_write_b64 per nt
      float rsn[4];
#pragma unroll
      for (int nt = 0; nt < 4; ++nt) {
        bf16x4 pk;
        float r0 = __expf(Sv[nt][0] - mrow);
        float r1 = __expf(Sv[nt][1] - mrow);
        float r2 = __expf(Sv[nt][2] - mrow);
        float r3 = __expf(Sv[nt][3] - mrow);
        pk[0] = (bf16_t)r0;
        pk[1] = (bf16_t)r1;
        pk[2] = (bf16_t)r2;
        pk[3] = (bf16_t)r3;
        rsn[nt] = (r0 + r1) + (r2 + r3);
        *(bf16x4*)&pw[l16 * 72 + nt * 16 + quad * 4] = pk;
      }
      float rs = (rsn[0] + rsn[1]) + (rsn[2] + rsn[3]);
      rs += __shfl_xor(rs, 16);
      rs += __shfl_xor(rs, 32);
      lrow += rs;

      // PV: P A-frag read back (wave-private tile; no barrier needed)
      bf16x8 pf0 = *(const bf16x8*)&pw[l16 * 72 + quad * 8];
      bf16x8 pf1 = *(const bf16x8*)&pw[l16 * 72 + 32 + quad * 8];
      __builtin_amdgcn_s_setprio(1);
#pragma unroll
      for (int dt = 0; dt < 4; ++dt) {
        bf16x8 vf0 = *(const bf16x8*)&Vt[(dt * 16 + l16) * 72 + quad * 8];
        bf16x8 vf1 = *(const bf16x8*)&Vt[(dt * 16 + l16) * 72 + 32 + quad * 8];
        Of[dt] = MFMA16(pf0, vf0, Of[dt]);
        Of[dt] = MFMA16(pf1, vf1, Of[dt]);
      }
      __builtin_amdgcn_s_setprio(0);
    }

    // epilogue: broadcast l to row domain, write O over this wave's Q rows
    float lr[4];
#pragma unroll
    for (int r = 0; r < 4; ++r) lr[r] = __shfl(lrow, quad * 4 + r, 16);
    const int t = Q0 + wave * 16 + quad * 4;
#pragma unroll
    for (int r = 0; r < 4; ++r) {
      const float inv = 1.0f / lr[r];
      bf16_t* op = base + (size_t)(t + r) * C3 + h * 64 + l16;
#pragma unroll
      for (int dt = 0; dt < 4; ++dt)
        op[dt * 16] = (bf16_t)(Of[dt][r] * inv);
    }
  }
}

// ---------------------------------------------------------------------------
// I/O contract (R8 probe): ALL inputs f32; output f32.
// ---------------------------------------------------------------------------
extern "C" void kernel_launch(void* const* d_in, const int* in_sizes, int n_in,
                              void* d_out, int out_size, void* d_ws,
                              size_t ws_size, hipStream_t stream) {
  constexpr int B = 4, T = 2048, C = 1024;
  constexpr int M = B * T;  // 8192

  const float* x = (const float*)d_in[0];
  const float* w_qkv = (const float*)d_in[1];
  const float* w_out = (const float*)d_in[2];
  const float* b_out = (const float*)d_in[3];
  for (int i = 0; i < n_in; ++i) {
    const long long s = in_sizes[i];
    if (s == (long long)M * C) x = (const float*)d_in[i];
    else if (s == (long long)3 * C * C) w_qkv = (const float*)d_in[i];
    else if (s == (long long)C * C) w_out = (const float*)d_in[i];
    else if (s == C) b_out = (const float*)d_in[i];
  }

  // bf16 copies of x and w_qkv live in d_out (32 MB): dead before the final
  // GEMM overwrites d_out. ws holds qkv [M,3C] bf16 = 48 MB (proven safe).
  bf16_t* xb = (bf16_t*)d_out;                    // 16 MB
  bf16_t* wqb = xb + (size_t)M * C;               // 6 MB
  bf16_t* qkv = (bf16_t*)d_ws;                    // 48 MB

  cvt_f32_bf16<<<1024, 256, 0, stream>>>(x, xb, (long long)M * C);
  cvt_f32_bf16<<<512, 256, 0, stream>>>(w_qkv, wqb, 3LL * C * C);

  // fused QKV: [M,3C] = xb @ wqb^T
  gemm_async<false, bf16_t, false>
      <<<dim3(3 * C / 128, M / 128), 256, 0, stream>>>(
          xb, C, wqb, nullptr, qkv, 3 * C, M, 3 * C, C);

  // attention in place (Q slot of qkv); work-balanced pairing grid
  attn_mfma<<<dim3(8, B * 16), 512, 0, stream>>>(qkv);

  // out = att @ w_out^T + b_out -> f32 d_out (overwrites xb/wqb, now dead)
  gemm_async<true, float, true><<<dim3(C / 128, M / 128), 256, 0, stream>>>(
      qkv, 3 * C, w_out, b_out, (float*)d_out, C, M, C, C);
}

// Round 2
// 265.111 us; speedup vs baseline: 1.2453x; 1.0798x over previous
//
#include <hip/hip_runtime.h>
#include <hip/hip_bf16.h>

typedef __bf16 bf16_t;
typedef __bf16 bf16x4 __attribute__((ext_vector_type(4)));
typedef __bf16 bf16x8 __attribute__((ext_vector_type(8)));
typedef float f32x4 __attribute__((ext_vector_type(4)));

#define MFMA16(a, b, c) __builtin_amdgcn_mfma_f32_16x16x32_bf16(a, b, c, 0, 0, 0)

// async 16B global->LDS (m97 pattern). lds ptr wave-uniform; lane writes
// ldsbase + lane*16.
__device__ __forceinline__ void gld16(const bf16_t* g, bf16_t* l) {
  __builtin_amdgcn_global_load_lds(
      (const __attribute__((address_space(1))) unsigned int*)(const void*)g,
      (__attribute__((address_space(3))) unsigned int*)(void*)l, 16, 0, 0);
}

// ---------------------------------------------------------------------------
// f32 -> bf16 elementwise convert (n multiple of 8)
// ---------------------------------------------------------------------------
__global__ __launch_bounds__(256) void cvt_f32_bf16(
    const float* __restrict__ src, bf16_t* __restrict__ dst, long long n) {
  long long i = ((long long)blockIdx.x * 256 + threadIdx.x) * 8;
  const long long stride = (long long)gridDim.x * 256 * 8;
  for (; i < n; i += stride) {
    f32x4 a = *(const f32x4*)(src + i);
    f32x4 b = *(const f32x4*)(src + i + 4);
    bf16x8 r;
#pragma unroll
    for (int e = 0; e < 4; ++e) {
      r[e] = (bf16_t)a[e];
      r[4 + e] = (bf16_t)b[e];
    }
    *(bf16x8*)(dst + i) = r;
  }
}

// ---------------------------------------------------------------------------
// GEMM: C[m][n] = sum_k A[m][k]*W[n][k] (+bias). A bf16 via global_load_lds.
// W: bf16 via global_load_lds (WF32=false) or f32 via cvt staging (true).
// 128x128 tile, 4 waves (2x2), 64x64/wave, BK=32. Layouts R5==R6 verified.
// ---------------------------------------------------------------------------
template <bool WF32, typename TC, bool BIAS>
__global__ __launch_bounds__(256, 2) void gemm_async(
    const bf16_t* __restrict__ A, int lda, const void* __restrict__ Wv,
    const float* __restrict__ bias, TC* __restrict__ C, int ldc,
    int M, int N, int K) {
  constexpr int BST = WF32 ? 40 : 32;
  __shared__ bf16_t As[128 * 32];   // unpadded: global_load_lds layout
  __shared__ bf16_t Bs[128 * BST];

  const int tid = threadIdx.x;
  const int i = tid & 63;
  const int w = tid >> 6;
  const int l16 = tid & 15;
  const int quad = (tid >> 4) & 3;
  const int wm = w & 1;
  const int wn = w >> 1;
  const int m0 = blockIdx.y * 128;
  const int n0 = blockIdx.x * 128;

  const bf16_t* ag = A + (size_t)(m0 + w * 32 + (i >> 2)) * lda + (i & 3) * 8;
  bf16_t* as0 = &As[(w * 32) * 32];
  bf16_t* as1 = &As[(w * 32 + 16) * 32];

  const bf16_t* bg = nullptr;
  bf16_t *bs0 = nullptr, *bs1 = nullptr;
  const float* wfg = nullptr;
  bf16_t* bsw = nullptr;
  if (!WF32) {
    bg = (const bf16_t*)Wv + (size_t)(n0 + w * 32 + (i >> 2)) * K + (i & 3) * 8;
    bs0 = &Bs[(w * 32) * 32];
    bs1 = &Bs[(w * 32 + 16) * 32];
  } else {
    const int srow = tid >> 1;
    const int scol = (tid & 1) * 16;
    wfg = (const float*)Wv + (size_t)(n0 + srow) * K + scol;
    bsw = &Bs[srow * BST + scol];
  }

  f32x4 acc[4][4] = {};

  for (int k0 = 0; k0 < K; k0 += 32) {
    __syncthreads();
    gld16(ag + k0, as0);
    gld16(ag + 16 * lda + k0, as1);
    if (!WF32) {
      gld16(bg + k0, bs0);
      gld16(bg + 16 * K + k0, bs1);
    } else {
      f32x4 a = *(const f32x4*)(wfg + k0);
      f32x4 b = *(const f32x4*)(wfg + k0 + 4);
      f32x4 c2 = *(const f32x4*)(wfg + k0 + 8);
      f32x4 d = *(const f32x4*)(wfg + k0 + 12);
      bf16x8 r0, r1;
#pragma unroll
      for (int e = 0; e < 4; ++e) {
        r0[e] = (bf16_t)a[e];
        r0[4 + e] = (bf16_t)b[e];
        r1[e] = (bf16_t)c2[e];
        r1[4 + e] = (bf16_t)d[e];
      }
      *(bf16x8*)(bsw) = r0;
      *(bf16x8*)(bsw + 8) = r1;
    }
    __syncthreads();

    bf16x8 af[4], bfr[4];
#pragma unroll
    for (int t = 0; t < 4; ++t) {
      af[t] = *(const bf16x8*)&As[(wm * 64 + t * 16 + l16) * 32 + quad * 8];
      bfr[t] = *(const bf16x8*)&Bs[(wn * 64 + t * 16 + l16) * BST + quad * 8];
    }
#pragma unroll
    for (int mi = 0; mi < 4; ++mi)
#pragma unroll
      for (int ni = 0; ni < 4; ++ni)
        acc[mi][ni] = MFMA16(af[mi], bfr[ni], acc[mi][ni]);
  }

#pragma unroll
  for (int ni = 0; ni < 4; ++ni) {
    const int col = n0 + wn * 64 + ni * 16 + l16;
    const float bv = BIAS ? bias[col] : 0.0f;
#pragma unroll
    for (int mi = 0; mi < 4; ++mi) {
      const int row = m0 + wm * 64 + mi * 16 + quad * 4;
#pragma unroll
      for (int r = 0; r < 4; ++r)
        C[(size_t)(row + r) * ldc + col] = (TC)(acc[mi][ni][r] + bv);
    }
  }
}

// ---------------------------------------------------------------------------
// Flash attention (causal), qkv interleaved [B*T, 3C] bf16 (q|k|v).
// Output overwrites the Q slot in place (R3-verified disjointness).
//
// Work-balanced: block p processes q-strips qt=p and qt=15-p -> every block
// does exactly 34 j-tiles. Grid (8, B*H) = 512 blocks of 512 threads.
//
// v2: swapped QK^T (S^T = mfma(K,Q)); lane holds a full q-row slice.
// v3 (this round):
//  * exp2-domain softmax: Q prescaled by 0.125*log2(e), so S comes out of
//    MFMA already in log2 units. P = exp2(S - m), alpha = exp2(dm). Saves
//    17 v_mul per tile (the x*log2e inside every __expf).
//  * wave-uniform mask skip: only the diagonal-overlap tile (j0+64 > qlo)
//    runs the 32-op causal mask; ~90% of tiles skip it entirely.
// ---------------------------------------------------------------------------
__global__ __launch_bounds__(512, 4) void attn_mfma(bf16_t* __restrict__ qkv) {
  constexpr int T = 2048, C3 = 3072, C = 1024;
  __shared__ bf16_t Ks[64 * 72];      // [token][d], +8 pad
  __shared__ bf16_t Vt[64 * 72];      // [d][token], +8 pad
  __shared__ bf16_t Ps[8 * 16 * 72];  // per-wave P tile [qrow][key]

  const int tid = threadIdx.x;
  const int wave = tid >> 6;        // 0..7
  const int lane = tid & 63;
  const int l16 = tid & 15;
  const int quad = (tid >> 4) & 3;
  const int p = blockIdx.x;         // 0..7 -> strips p and 15-p
  const int b = blockIdx.y >> 4;
  const int h = blockIdx.y & 15;
  bf16_t* base = qkv + (size_t)b * T * C3;

  // 1/sqrt(64) * log2(e): softmax entirely in exp2 domain.
  const float QSCALE = 0.125f * 1.44269504088896340736f;

  // K staging map (waves 0-3): token = tid>>2 (0..63), 16 d's at (tid&3)*16
  const int kst = tid >> 2;
  const int ksd = (tid & 3) * 16;
  // V staging map (waves 4-7): token = lane, 16 d's at (wave-4)*16
  const int vtok = lane;
  const int vdg = (wave - 4) * 16;

  bf16_t* pw = &Ps[wave * 16 * 72];

  bf16x8 st0, st1;  // staging regs: K halves (waves 0-3) or V halves (4-7)

  for (int s = 0; s < 2; ++s) {
    const int qt = (s == 0) ? p : 15 - p;
    const int Q0 = qt * 128;
    const int qlo = Q0 + wave * 16;
    const int jmax = Q0 + 64;

    // Q fragments, prescaled by 0.125*log2e (one extra bf16 rounding on Q)
    bf16x8 qf[2];
    {
      const bf16_t* qp = base + (size_t)(qlo + l16) * C3 + h * 64 + quad * 8;
      bf16x8 a = *(const bf16x8*)qp;
      bf16x8 c = *(const bf16x8*)(qp + 32);
#pragma unroll
      for (int e = 0; e < 8; ++e) {
        a[e] = (bf16_t)((float)a[e] * QSCALE);
        c[e] = (bf16_t)((float)c[e] * QSCALE);
      }
      qf[0] = a;
      qf[1] = c;
    }

    f32x4 Of[4] = {};
    float mrow = -1e30f;
    float lrow = 0.f;

    // prologue: issue tile-0 loads into regs (T14 split)
    if (wave < 4) {
      const bf16_t* kp = base + (size_t)kst * C3 + C + h * 64 + ksd;
      st0 = *(const bf16x8*)kp;
      st1 = *(const bf16x8*)(kp + 8);
    } else {
      const bf16_t* vp = base + (size_t)vtok * C3 + 2 * C + h * 64 + vdg;
      st0 = *(const bf16x8*)vp;
      st1 = *(const bf16x8*)(vp + 8);
    }

    for (int j0 = 0; j0 <= jmax; j0 += 64) {
      __syncthreads();  // previous tile's Ks/Vt readers are done
      // commit staged regs -> LDS (implicit vmcnt wait on st0/st1)
      if (wave < 4) {
        *(bf16x8*)&Ks[kst * 72 + ksd] = st0;
        *(bf16x8*)&Ks[kst * 72 + ksd + 8] = st1;
      } else {
#pragma unroll
        for (int e = 0; e < 8; ++e) {
          Vt[(vdg + e) * 72 + vtok] = st0[e];
          Vt[(vdg + 8 + e) * 72 + vtok] = st1[e];
        }
      }
      // issue next tile's loads; latency hides under compute below
      if (j0 + 64 <= jmax) {
        const int jn = j0 + 64;
        if (wave < 4) {
          const bf16_t* kp = base + (size_t)(jn + kst) * C3 + C + h * 64 + ksd;
          st0 = *(const bf16x8*)kp;
          st1 = *(const bf16x8*)(kp + 8);
        } else {
          const bf16_t* vp =
              base + (size_t)(jn + vtok) * C3 + 2 * C + h * 64 + vdg;
          st0 = *(const bf16x8*)vp;
          st1 = *(const bf16x8*)(vp + 8);
        }
      }
      __syncthreads();

      if (qlo + 15 < j0) continue;  // wave-uniform: fully-masked wave skips

      // S^T tile: lane holds S[qlo+l16][j0 + nt*16 + quad*4 + r]
      float Sv[4][4];
      const int qrow = qlo + l16;
      __builtin_amdgcn_s_setprio(1);
#pragma unroll
      for (int nt = 0; nt < 4; ++nt) {
        f32x4 sacc = {};
#pragma unroll
        for (int s2 = 0; s2 < 2; ++s2) {
          bf16x8 kf =
              *(const bf16x8*)&Ks[(nt * 16 + l16) * 72 + s2 * 32 + quad * 8];
          sacc = MFMA16(kf, qf[s2], sacc);  // swapped: rows=keys, cols=qrows
        }
#pragma unroll
        for (int r = 0; r < 4; ++r) Sv[nt][r] = sacc[r];
      }
      __builtin_amdgcn_s_setprio(0);

      // causal mask: only the diagonal-overlap tile needs it (wave-uniform)
      if (j0 + 64 > qlo) {
#pragma unroll
        for (int nt = 0; nt < 4; ++nt) {
          const int keyb = j0 + nt * 16 + quad * 4;
#pragma unroll
          for (int r = 0; r < 4; ++r)
            if (keyb + r > qrow) Sv[nt][r] = -1e30f;
        }
      }

      // tile max for this lane's row (tree, then cross-quad)
      float vm[4];
#pragma unroll
      for (int nt = 0; nt < 4; ++nt)
        vm[nt] = fmaxf(fmaxf(Sv[nt][0], Sv[nt][1]),
                       fmaxf(Sv[nt][2], Sv[nt][3]));
      float v = fmaxf(fmaxf(vm[0], vm[1]), fmaxf(vm[2], vm[3]));
      v = fmaxf(v, __shfl_xor(v, 16));
      v = fmaxf(v, __shfl_xor(v, 32));

      // exact defer-skip: when no row grew, alpha==1 exactly -> skip rescale
      if (__any(v > mrow)) {
        const float mnew = fmaxf(mrow, v);
        const float alpha = __builtin_amdgcn_exp2f(mrow - mnew);
        mrow = mnew;
        lrow *= alpha;
        float ar[4];
#pragma unroll
        for (int r = 0; r < 4; ++r) ar[r] = __shfl(alpha, quad * 4 + r, 16);
#pragma unroll
        for (int dt = 0; dt < 4; ++dt)
#pragma unroll
          for (int r = 0; r < 4; ++r) Of[dt][r] *= ar[r];
      }

      // P = exp2(S - m); pack 4 consecutive keys -> one ds_write_b64 per nt
      float rsn[4];
#pragma unroll
      for (int nt = 0; nt < 4; ++nt) {
        bf16x4 pk;
        float r0 = __builtin_amdgcn_exp2f(Sv[nt][0] - mrow);
        float r1 = __builtin_amdgcn_exp2f(Sv[nt][1] - mrow);
        float r2 = __builtin_amdgcn_exp2f(Sv[nt][2] - mrow);
        float r3 = __builtin_amdgcn_exp2f(Sv[nt][3] - mrow);
        pk[0] = (bf16_t)r0;
        pk[1] = (bf16_t)r1;
        pk[2] = (bf16_t)r2;
        pk[3] = (bf16_t)r3;
        rsn[nt] = (r0 + r1) + (r2 + r3);
        *(bf16x4*)&pw[l16 * 72 + nt * 16 + quad * 4] = pk;
      }
      float rs = (rsn[0] + rsn[1]) + (rsn[2] + rsn[3]);
      rs += __shfl_xor(rs, 16);
      rs += __shfl_xor(rs, 32);
      lrow += rs;

      // PV: P A-frag read back (wave-private tile; no barrier needed)
      bf16x8 pf0 = *(const bf16x8*)&pw[l16 * 72 + quad * 8];
      bf16x8 pf1 = *(const bf16x8*)&pw[l16 * 72 + 32 + quad * 8];
      __builtin_amdgcn_s_setprio(1);
#pragma unroll
      for (int dt = 0; dt < 4; ++dt) {
        bf16x8 vf0 = *(const bf16x8*)&Vt[(dt * 16 + l16) * 72 + quad * 8];
        bf16x8 vf1 = *(const bf16x8*)&Vt[(dt * 16 + l16) * 72 + 32 + quad * 8];
        Of[dt] = MFMA16(pf0, vf0, Of[dt]);
        Of[dt] = MFMA16(pf1, vf1, Of[dt]);
      }
      __builtin_amdgcn_s_setprio(0);
    }

    // epilogue: broadcast l to row domain, write O over this wave's Q rows
    float lr[4];
#pragma unroll
    for (int r = 0; r < 4; ++r) lr[r] = __shfl(lrow, quad * 4 + r, 16);
    const int t = Q0 + wave * 16 + quad * 4;
#pragma unroll
    for (int r = 0; r < 4; ++r) {
      const float inv = 1.0f / lr[r];
      bf16_t* op = base + (size_t)(t + r) * C3 + h * 64 + l16;
#pragma unroll
      for (int dt = 0; dt < 4; ++dt)
        op[dt * 16] = (bf16_t)(Of[dt][r] * inv);
    }
  }
}

// ---------------------------------------------------------------------------
// I/O contract (R8 probe): ALL inputs f32; output f32.
// ---------------------------------------------------------------------------
extern "C" void kernel_launch(void* const* d_in, const int* in_sizes, int n_in,
                              void* d_out, int out_size, void* d_ws,
                              size_t ws_size, hipStream_t stream) {
  constexpr int B = 4, T = 2048, C = 1024;
  constexpr int M = B * T;  // 8192

  const float* x = (const float*)d_in[0];
  const float* w_qkv = (const float*)d_in[1];
  const float* w_out = (const float*)d_in[2];
  const float* b_out = (const float*)d_in[3];
  for (int i = 0; i < n_in; ++i) {
    const long long s = in_sizes[i];
    if (s == (long long)M * C) x = (const float*)d_in[i];
    else if (s == (long long)3 * C * C) w_qkv = (const float*)d_in[i];
    else if (s == (long long)C * C) w_out = (const float*)d_in[i];
    else if (s == C) b_out = (const float*)d_in[i];
  }

  // bf16 copies of x and w_qkv live in d_out (32 MB): dead before the final
  // GEMM overwrites d_out. ws holds qkv [M,3C] bf16 = 48 MB (proven safe);
  // if ws has 2 MB more, a bf16 copy of w_out lives after qkv so the final
  // GEMM can use the fast global_load_lds path instead of WF32 staging.
  bf16_t* xb = (bf16_t*)d_out;                    // 16 MB
  bf16_t* wqb = xb + (size_t)M * C;               // 6 MB
  bf16_t* qkv = (bf16_t*)d_ws;                    // 48 MB
  bf16_t* wob = qkv + (size_t)M * 3 * C;          // +2 MB (guarded)
  const bool ws_ok =
      ws_size >= (size_t)M * 3 * C * 2 + (size_t)C * C * 2;

  cvt_f32_bf16<<<1024, 256, 0, stream>>>(x, xb, (long long)M * C);
  cvt_f32_bf16<<<512, 256, 0, stream>>>(w_qkv, wqb, 3LL * C * C);
  if (ws_ok)
    cvt_f32_bf16<<<256, 256, 0, stream>>>(w_out, wob, (long long)C * C);

  // fused QKV: [M,3C] = xb @ wqb^T
  gemm_async<false, bf16_t, false>
      <<<dim3(3 * C / 128, M / 128), 256, 0, stream>>>(
          xb, C, wqb, nullptr, qkv, 3 * C, M, 3 * C, C);

  // attention in place (Q slot of qkv); work-balanced pairing grid
  attn_mfma<<<dim3(8, B * 16), 512, 0, stream>>>(qkv);

  // out = att @ w_out^T + b_out -> f32 d_out (overwrites xb/wqb, now dead)
  if (ws_ok)
    gemm_async<false, float, true><<<dim3(C / 128, M / 128), 256, 0, stream>>>(
        qkv, 3 * C, wob, b_out, (float*)d_out, C, M, C, C);
  else
    gemm_async<true, float, true><<<dim3(C / 128, M / 128), 256, 0, stream>>>(
        qkv, 3 * C, w_out, b_out, (float*)d_out, C, M, C, C);
}

// Round 3
// 260.517 us; speedup vs baseline: 1.2673x; 1.0176x over previous
//
#include <hip/hip_runtime.h>
#include <hip/hip_bf16.h>

typedef __bf16 bf16_t;
typedef __bf16 bf16x4 __attribute__((ext_vector_type(4)));
typedef __bf16 bf16x8 __attribute__((ext_vector_type(8)));
typedef float f32x4 __attribute__((ext_vector_type(4)));

#define MFMA16(a, b, c) __builtin_amdgcn_mfma_f32_16x16x32_bf16(a, b, c, 0, 0, 0)

// async 16B global->LDS (m97 pattern). lds ptr wave-uniform; lane writes
// ldsbase + lane*16.
__device__ __forceinline__ void gld16(const bf16_t* g, bf16_t* l) {
  __builtin_amdgcn_global_load_lds(
      (const __attribute__((address_space(1))) unsigned int*)(const void*)g,
      (__attribute__((address_space(3))) unsigned int*)(void*)l, 16, 0, 0);
}

// ---------------------------------------------------------------------------
// f32 -> bf16 elementwise convert (n multiple of 8)
// ---------------------------------------------------------------------------
__global__ __launch_bounds__(256) void cvt_f32_bf16(
    const float* __restrict__ src, bf16_t* __restrict__ dst, long long n) {
  long long i = ((long long)blockIdx.x * 256 + threadIdx.x) * 8;
  const long long stride = (long long)gridDim.x * 256 * 8;
  for (; i < n; i += stride) {
    f32x4 a = *(const f32x4*)(src + i);
    f32x4 b = *(const f32x4*)(src + i + 4);
    bf16x8 r;
#pragma unroll
    for (int e = 0; e < 4; ++e) {
      r[e] = (bf16_t)a[e];
      r[4 + e] = (bf16_t)b[e];
    }
    *(bf16x8*)(dst + i) = r;
  }
}

// ---------------------------------------------------------------------------
// GEMM: C[m][n] = sum_k A[m][k]*W[n][k] (+bias). A bf16 via global_load_lds.
// W: bf16 via global_load_lds (WF32=false) or f32 via reg-staging (true).
// 128x128 tile, 4 waves (2x2), 64x64/wave, BK=32.
//
// v4 (this round): T3 "minimum 2-phase" double-buffer — issue next K-tile's
// global_load_lds BEFORE computing the current one; ONE barrier per K-step
// (its implicit vmcnt(0) lands after ds_read+MFMA covered the latency).
// Previous version drained vmcnt(0) immediately after issue: full load
// latency exposed every K-step. Also T1 bijective XCD swizzle (nwg%8==0).
// Race audit: gld16 writes buf[cur^1], readers touch buf[cur] (disjoint);
// cross-iteration overlap blocked by the per-step barrier (waves pass only
// after their lgkmcnt AND vmcnt drain).
// ---------------------------------------------------------------------------
template <bool WF32, typename TC, bool BIAS>
__global__ __launch_bounds__(256, 2) void gemm_async(
    const bf16_t* __restrict__ A, int lda, const void* __restrict__ Wv,
    const float* __restrict__ bias, TC* __restrict__ C, int ldc,
    int M, int N, int K) {
  constexpr int BST = WF32 ? 40 : 32;
  __shared__ bf16_t As[2][128 * 32];   // unpadded: global_load_lds layout
  __shared__ bf16_t Bs[2][128 * BST];

  const int tid = threadIdx.x;
  const int i = tid & 63;
  const int w = tid >> 6;
  const int l16 = tid & 15;
  const int quad = (tid >> 4) & 3;
  const int wm = w & 1;
  const int wn = w >> 1;

  // T1: bijective XCD swizzle (requires nwg % 8 == 0; both grids satisfy)
  const int nwg = gridDim.x * gridDim.y;
  int wg = blockIdx.y * gridDim.x + blockIdx.x;
  if ((nwg & 7) == 0) wg = (wg & 7) * (nwg >> 3) + (wg >> 3);
  const int m0 = (wg / gridDim.x) * 128;
  const int n0 = (wg % gridDim.x) * 128;

  const bf16_t* ag = A + (size_t)(m0 + w * 32 + (i >> 2)) * lda + (i & 3) * 8;
  bf16_t* as0[2] = {&As[0][(w * 32) * 32], &As[1][(w * 32) * 32]};
  bf16_t* as1[2] = {&As[0][(w * 32 + 16) * 32], &As[1][(w * 32 + 16) * 32]};

  const bf16_t* bg = nullptr;
  bf16_t *bs0[2] = {nullptr, nullptr}, *bs1[2] = {nullptr, nullptr};
  const float* wfg = nullptr;
  bf16_t* bsw[2] = {nullptr, nullptr};
  if (!WF32) {
    bg = (const bf16_t*)Wv + (size_t)(n0 + w * 32 + (i >> 2)) * K + (i & 3) * 8;
    bs0[0] = &Bs[0][(w * 32) * 32];
    bs0[1] = &Bs[1][(w * 32) * 32];
    bs1[0] = &Bs[0][(w * 32 + 16) * 32];
    bs1[1] = &Bs[1][(w * 32 + 16) * 32];
  } else {
    const int srow = tid >> 1;
    const int scol = (tid & 1) * 16;
    wfg = (const float*)Wv + (size_t)(n0 + srow) * K + scol;
    bsw[0] = &Bs[0][srow * BST + scol];
    bsw[1] = &Bs[1][srow * BST + scol];
  }

  f32x4 acc[4][4] = {};

  // ---- prologue: stage K-tile 0 into buffer 0 ----
  gld16(ag, as0[0]);
  gld16(ag + 16 * lda, as1[0]);
  if (!WF32) {
    gld16(bg, bs0[0]);
    gld16(bg + 16 * K, bs1[0]);
  } else {
    f32x4 a = *(const f32x4*)(wfg);
    f32x4 b = *(const f32x4*)(wfg + 4);
    f32x4 c2 = *(const f32x4*)(wfg + 8);
    f32x4 d = *(const f32x4*)(wfg + 12);
    bf16x8 r0, r1;
#pragma unroll
    for (int e = 0; e < 4; ++e) {
      r0[e] = (bf16_t)a[e];
      r0[4 + e] = (bf16_t)b[e];
      r1[e] = (bf16_t)c2[e];
      r1[4 + e] = (bf16_t)d[e];
    }
    *(bf16x8*)(bsw[0]) = r0;
    *(bf16x8*)(bsw[0] + 8) = r1;
  }
  __syncthreads();  // implicit vmcnt(0): tile 0 resident

  int cur = 0;
  for (int k0 = 0; k0 < K; k0 += 32) {
    const bool has_next = (k0 + 32 < K);
    const int nxt = cur ^ 1;
    f32x4 wa, wb, wc, wd;  // WF32 staging regs (issued early, used late)

    // issue next tile's loads -> other buffer (in flight during compute)
    if (has_next) {
      gld16(ag + k0 + 32, as0[nxt]);
      gld16(ag + 16 * lda + k0 + 32, as1[nxt]);
      if (!WF32) {
        gld16(bg + k0 + 32, bs0[nxt]);
        gld16(bg + 16 * K + k0 + 32, bs1[nxt]);
      } else {
        wa = *(const f32x4*)(wfg + k0 + 32);
        wb = *(const f32x4*)(wfg + k0 + 36);
        wc = *(const f32x4*)(wfg + k0 + 40);
        wd = *(const f32x4*)(wfg + k0 + 44);
      }
    }

    // compute current tile
    bf16x8 af[4], bfr[4];
#pragma unroll
    for (int t = 0; t < 4; ++t) {
      af[t] = *(const bf16x8*)&As[cur][(wm * 64 + t * 16 + l16) * 32 + quad * 8];
      bfr[t] =
          *(const bf16x8*)&Bs[cur][(wn * 64 + t * 16 + l16) * BST + quad * 8];
    }
    __builtin_amdgcn_s_setprio(1);
#pragma unroll
    for (int mi = 0; mi < 4; ++mi)
#pragma unroll
      for (int ni = 0; ni < 4; ++ni)
        acc[mi][ni] = MFMA16(af[mi], bfr[ni], acc[mi][ni]);
    __builtin_amdgcn_s_setprio(0);

    // WF32: convert + commit staged regs (vmcnt waits here, after MFMA)
    if (WF32 && has_next) {
      bf16x8 r0, r1;
#pragma unroll
      for (int e = 0; e < 4; ++e) {
        r0[e] = (bf16_t)wa[e];
        r0[4 + e] = (bf16_t)wb[e];
        r1[e] = (bf16_t)wc[e];
        r1[4 + e] = (bf16_t)wd[e];
      }
      *(bf16x8*)(bsw[nxt]) = r0;
      *(bf16x8*)(bsw[nxt] + 8) = r1;
    }

    __syncthreads();  // drains vmcnt+lgkmcnt; next tile resident, cur free
    cur = nxt;
  }

#pragma unroll
  for (int ni = 0; ni < 4; ++ni) {
    const int col = n0 + wn * 64 + ni * 16 + l16;
    const float bv = BIAS ? bias[col] : 0.0f;
#pragma unroll
    for (int mi = 0; mi < 4; ++mi) {
      const int row = m0 + wm * 64 + mi * 16 + quad * 4;
#pragma unroll
      for (int r = 0; r < 4; ++r)
        C[(size_t)(row + r) * ldc + col] = (TC)(acc[mi][ni][r] + bv);
    }
  }
}

// ---------------------------------------------------------------------------
// Flash attention (causal), qkv interleaved [B*T, 3C] bf16 (q|k|v).
// Output overwrites the Q slot in place (R3-verified disjointness).
//
// Work-balanced: block p processes q-strips qt=p and qt=15-p -> every block
// does exactly 34 j-tiles. Grid (8, B*H) = 512 blocks of 512 threads.
//
// v2: swapped QK^T (S^T = mfma(K,Q)); lane holds a full q-row slice.
// v3: exp2-domain softmax (Q prescaled by 0.125*log2e); wave-uniform
//     diagonal-only causal mask; exact defer-skip rescale; T14 async-STAGE;
//     setprio around MFMA clusters.
// ---------------------------------------------------------------------------
__global__ __launch_bounds__(512, 4) void attn_mfma(bf16_t* __restrict__ qkv) {
  constexpr int T = 2048, C3 = 3072, C = 1024;
  __shared__ bf16_t Ks[64 * 72];      // [token][d], +8 pad
  __shared__ bf16_t Vt[64 * 72];      // [d][token], +8 pad
  __shared__ bf16_t Ps[8 * 16 * 72];  // per-wave P tile [qrow][key]

  const int tid = threadIdx.x;
  const int wave = tid >> 6;        // 0..7
  const int lane = tid & 63;
  const int l16 = tid & 15;
  const int quad = (tid >> 4) & 3;
  const int p = blockIdx.x;         // 0..7 -> strips p and 15-p
  const int b = blockIdx.y >> 4;
  const int h = blockIdx.y & 15;
  bf16_t* base = qkv + (size_t)b * T * C3;

  // 1/sqrt(64) * log2(e): softmax entirely in exp2 domain.
  const float QSCALE = 0.125f * 1.44269504088896340736f;

  // K staging map (waves 0-3): token = tid>>2 (0..63), 16 d's at (tid&3)*16
  const int kst = tid >> 2;
  const int ksd = (tid & 3) * 16;
  // V staging map (waves 4-7): token = lane, 16 d's at (wave-4)*16
  const int vtok = lane;
  const int vdg = (wave - 4) * 16;

  bf16_t* pw = &Ps[wave * 16 * 72];

  bf16x8 st0, st1;  // staging regs: K halves (waves 0-3) or V halves (4-7)

  for (int s = 0; s < 2; ++s) {
    const int qt = (s == 0) ? p : 15 - p;
    const int Q0 = qt * 128;
    const int qlo = Q0 + wave * 16;
    const int jmax = Q0 + 64;

    // Q fragments, prescaled by 0.125*log2e (one extra bf16 rounding on Q)
    bf16x8 qf[2];
    {
      const bf16_t* qp = base + (size_t)(qlo + l16) * C3 + h * 64 + quad * 8;
      bf16x8 a = *(const bf16x8*)qp;
      bf16x8 c = *(const bf16x8*)(qp + 32);
#pragma unroll
      for (int e = 0; e < 8; ++e) {
        a[e] = (bf16_t)((float)a[e] * QSCALE);
        c[e] = (bf16_t)((float)c[e] * QSCALE);
      }
      qf[0] = a;
      qf[1] = c;
    }

    f32x4 Of[4] = {};
    float mrow = -1e30f;
    float lrow = 0.f;

    // prologue: issue tile-0 loads into regs (T14 split)
    if (wave < 4) {
      const bf16_t* kp = base + (size_t)kst * C3 + C + h * 64 + ksd;
      st0 = *(const bf16x8*)kp;
      st1 = *(const bf16x8*)(kp + 8);
    } else {
      const bf16_t* vp = base + (size_t)vtok * C3 + 2 * C + h * 64 + vdg;
      st0 = *(const bf16x8*)vp;
      st1 = *(const bf16x8*)(vp + 8);
    }

    for (int j0 = 0; j0 <= jmax; j0 += 64) {
      __syncthreads();  // previous tile's Ks/Vt readers are done
      // commit staged regs -> LDS (implicit vmcnt wait on st0/st1)
      if (wave < 4) {
        *(bf16x8*)&Ks[kst * 72 + ksd] = st0;
        *(bf16x8*)&Ks[kst * 72 + ksd + 8] = st1;
      } else {
#pragma unroll
        for (int e = 0; e < 8; ++e) {
          Vt[(vdg + e) * 72 + vtok] = st0[e];
          Vt[(vdg + 8 + e) * 72 + vtok] = st1[e];
        }
      }
      // issue next tile's loads; latency hides under compute below
      if (j0 + 64 <= jmax) {
        const int jn = j0 + 64;
        if (wave < 4) {
          const bf16_t* kp = base + (size_t)(jn + kst) * C3 + C + h * 64 + ksd;
          st0 = *(const bf16x8*)kp;
          st1 = *(const bf16x8*)(kp + 8);
        } else {
          const bf16_t* vp =
              base + (size_t)(jn + vtok) * C3 + 2 * C + h * 64 + vdg;
          st0 = *(const bf16x8*)vp;
          st1 = *(const bf16x8*)(vp + 8);
        }
      }
      __syncthreads();

      if (qlo + 15 < j0) continue;  // wave-uniform: fully-masked wave skips

      // S^T tile: lane holds S[qlo+l16][j0 + nt*16 + quad*4 + r]
      float Sv[4][4];
      const int qrow = qlo + l16;
      __builtin_amdgcn_s_setprio(1);
#pragma unroll
      for (int nt = 0; nt < 4; ++nt) {
        f32x4 sacc = {};
#pragma unroll
        for (int s2 = 0; s2 < 2; ++s2) {
          bf16x8 kf =
              *(const bf16x8*)&Ks[(nt * 16 + l16) * 72 + s2 * 32 + quad * 8];
          sacc = MFMA16(kf, qf[s2], sacc);  // swapped: rows=keys, cols=qrows
        }
#pragma unroll
        for (int r = 0; r < 4; ++r) Sv[nt][r] = sacc[r];
      }
      __builtin_amdgcn_s_setprio(0);

      // causal mask: only the diagonal-overlap tile needs it (wave-uniform)
      if (j0 + 64 > qlo) {
#pragma unroll
        for (int nt = 0; nt < 4; ++nt) {
          const int keyb = j0 + nt * 16 + quad * 4;
#pragma unroll
          for (int r = 0; r < 4; ++r)
            if (keyb + r > qrow) Sv[nt][r] = -1e30f;
        }
      }

      // tile max for this lane's row (tree, then cross-quad)
      float vm[4];
#pragma unroll
      for (int nt = 0; nt < 4; ++nt)
        vm[nt] = fmaxf(fmaxf(Sv[nt][0], Sv[nt][1]),
                       fmaxf(Sv[nt][2], Sv[nt][3]));
      float v = fmaxf(fmaxf(vm[0], vm[1]), fmaxf(vm[2], vm[3]));
      v = fmaxf(v, __shfl_xor(v, 16));
      v = fmaxf(v, __shfl_xor(v, 32));

      // exact defer-skip: when no row grew, alpha==1 exactly -> skip rescale
      if (__any(v > mrow)) {
        const float mnew = fmaxf(mrow, v);
        const float alpha = __builtin_amdgcn_exp2f(mrow - mnew);
        mrow = mnew;
        lrow *= alpha;
        float ar[4];
#pragma unroll
        for (int r = 0; r < 4; ++r) ar[r] = __shfl(alpha, quad * 4 + r, 16);
#pragma unroll
        for (int dt = 0; dt < 4; ++dt)
#pragma unroll
          for (int r = 0; r < 4; ++r) Of[dt][r] *= ar[r];
      }

      // P = exp2(S - m); pack 4 consecutive keys -> one ds_write_b64 per nt
      float rsn[4];
#pragma unroll
      for (int nt = 0; nt < 4; ++nt) {
        bf16x4 pk;
        float r0 = __builtin_amdgcn_exp2f(Sv[nt][0] - mrow);
        float r1 = __builtin_amdgcn_exp2f(Sv[nt][1] - mrow);
        float r2 = __builtin_amdgcn_exp2f(Sv[nt][2] - mrow);
        float r3 = __builtin_amdgcn_exp2f(Sv[nt][3] - mrow);
        pk[0] = (bf16_t)r0;
        pk[1] = (bf16_t)r1;
        pk[2] = (bf16_t)r2;
        pk[3] = (bf16_t)r3;
        rsn[nt] = (r0 + r1) + (r2 + r3);
        *(bf16x4*)&pw[l16 * 72 + nt * 16 + quad * 4] = pk;
      }
      float rs = (rsn[0] + rsn[1]) + (rsn[2] + rsn[3]);
      rs += __shfl_xor(rs, 16);
      rs += __shfl_xor(rs, 32);
      lrow += rs;

      // PV: P A-frag read back (wave-private tile; no barrier needed)
      bf16x8 pf0 = *(const bf16x8*)&pw[l16 * 72 + quad * 8];
      bf16x8 pf1 = *(const bf16x8*)&pw[l16 * 72 + 32 + quad * 8];
      __builtin_amdgcn_s_setprio(1);
#pragma unroll
      for (int dt = 0; dt < 4; ++dt) {
        bf16x8 vf0 = *(const bf16x8*)&Vt[(dt * 16 + l16) * 72 + quad * 8];
        bf16x8 vf1 = *(const bf16x8*)&Vt[(dt * 16 + l16) * 72 + 32 + quad * 8];
        Of[dt] = MFMA16(pf0, vf0, Of[dt]);
        Of[dt] = MFMA16(pf1, vf1, Of[dt]);
      }
      __builtin_amdgcn_s_setprio(0);
    }

    // epilogue: broadcast l to row domain, write O over this wave's Q rows
    float lr[4];
#pragma unroll
    for (int r = 0; r < 4; ++r) lr[r] = __shfl(lrow, quad * 4 + r, 16);
    const int t = Q0 + wave * 16 + quad * 4;
#pragma unroll
    for (int r = 0; r < 4; ++r) {
      const float inv = 1.0f / lr[r];
      bf16_t* op = base + (size_t)(t + r) * C3 + h * 64 + l16;
#pragma unroll
      for (int dt = 0; dt < 4; ++dt)
        op[dt * 16] = (bf16_t)(Of[dt][r] * inv);
    }
  }
}

// ---------------------------------------------------------------------------
// I/O contract (R8 probe): ALL inputs f32; output f32.
// ---------------------------------------------------------------------------
extern "C" void kernel_launch(void* const* d_in, const int* in_sizes, int n_in,
                              void* d_out, int out_size, void* d_ws,
                              size_t ws_size, hipStream_t stream) {
  constexpr int B = 4, T = 2048, C = 1024;
  constexpr int M = B * T;  // 8192

  const float* x = (const float*)d_in[0];
  const float* w_qkv = (const float*)d_in[1];
  const float* w_out = (const float*)d_in[2];
  const float* b_out = (const float*)d_in[3];
  for (int i = 0; i < n_in; ++i) {
    const long long s = in_sizes[i];
    if (s == (long long)M * C) x = (const float*)d_in[i];
    else if (s == (long long)3 * C * C) w_qkv = (const float*)d_in[i];
    else if (s == (long long)C * C) w_out = (const float*)d_in[i];
    else if (s == C) b_out = (const float*)d_in[i];
  }

  // bf16 copies of x and w_qkv live in d_out (32 MB): dead before the final
  // GEMM overwrites d_out. ws holds qkv [M,3C] bf16 = 48 MB (proven safe);
  // if ws has 2 MB more, a bf16 copy of w_out lives after qkv so the final
  // GEMM can use the fast global_load_lds path instead of WF32 staging.
  bf16_t* xb = (bf16_t*)d_out;                    // 16 MB
  bf16_t* wqb = xb + (size_t)M * C;               // 6 MB
  bf16_t* qkv = (bf16_t*)d_ws;                    // 48 MB
  bf16_t* wob = qkv + (size_t)M * 3 * C;          // +2 MB (guarded)
  const bool ws_ok =
      ws_size >= (size_t)M * 3 * C * 2 + (size_t)C * C * 2;

  cvt_f32_bf16<<<1024, 256, 0, stream>>>(x, xb, (long long)M * C);
  cvt_f32_bf16<<<512, 256, 0, stream>>>(w_qkv, wqb, 3LL * C * C);
  if (ws_ok)
    cvt_f32_bf16<<<256, 256, 0, stream>>>(w_out, wob, (long long)C * C);

  // fused QKV: [M,3C] = xb @ wqb^T
  gemm_async<false, bf16_t, false>
      <<<dim3(3 * C / 128, M / 128), 256, 0, stream>>>(
          xb, C, wqb, nullptr, qkv, 3 * C, M, 3 * C, C);

  // attention in place (Q slot of qkv); work-balanced pairing grid
  attn_mfma<<<dim3(8, B * 16), 512, 0, stream>>>(qkv);

  // out = att @ w_out^T + b_out -> f32 d_out (overwrites xb/wqb, now dead)
  if (ws_ok)
    gemm_async<false, float, true><<<dim3(C / 128, M / 128), 256, 0, stream>>>(
        qkv, 3 * C, wob, b_out, (float*)d_out, C, M, C, C);
  else
    gemm_async<true, float, true><<<dim3(C / 128, M / 128), 256, 0, stream>>>(
        qkv, 3 * C, w_out, b_out, (float*)d_out, C, M, C, C);
}

// Round 4
// 254.339 us; speedup vs baseline: 1.2981x; 1.0243x over previous
//
#include <hip/hip_runtime.h>
#include <hip/hip_bf16.h>

typedef __bf16 bf16_t;
typedef __bf16 bf16x4 __attribute__((ext_vector_type(4)));
typedef __bf16 bf16x8 __attribute__((ext_vector_type(8)));
typedef float f32x4 __attribute__((ext_vector_type(4)));

#define MFMA16(a, b, c) __builtin_amdgcn_mfma_f32_16x16x32_bf16(a, b, c, 0, 0, 0)

// async 16B global->LDS (m97 pattern). lds ptr wave-uniform; lane writes
// ldsbase + lane*16.
__device__ __forceinline__ void gld16(const bf16_t* g, bf16_t* l) {
  __builtin_amdgcn_global_load_lds(
      (const __attribute__((address_space(1))) unsigned int*)(const void*)g,
      (__attribute__((address_space(3))) unsigned int*)(void*)l, 16, 0, 0);
}

// ---------------------------------------------------------------------------
// f32 -> bf16 elementwise convert (n multiple of 8)
// ---------------------------------------------------------------------------
__global__ __launch_bounds__(256) void cvt_f32_bf16(
    const float* __restrict__ src, bf16_t* __restrict__ dst, long long n) {
  long long i = ((long long)blockIdx.x * 256 + threadIdx.x) * 8;
  const long long stride = (long long)gridDim.x * 256 * 8;
  for (; i < n; i += stride) {
    f32x4 a = *(const f32x4*)(src + i);
    f32x4 b = *(const f32x4*)(src + i + 4);
    bf16x8 r;
#pragma unroll
    for (int e = 0; e < 4; ++e) {
      r[e] = (bf16_t)a[e];
      r[4 + e] = (bf16_t)b[e];
    }
    *(bf16x8*)(dst + i) = r;
  }
}

// ---------------------------------------------------------------------------
// GEMM: C[m][n] = sum_k A[m][k]*W[n][k] (+bias). A bf16 via global_load_lds.
// W: bf16 via global_load_lds (WF32=false) or f32 via reg-staging (true).
// 128x128 tile, 4 waves (2x2), 64x64/wave, BK=32, 2-phase double-buffer.
//
// v5 (this round): __launch_bounds__(256, 3) — v4's (256,2) let the
// allocator use >170 VGPR, capping occupancy at 2 blocks/CU. The kernel
// needs ~125 VGPR; requesting 3 waves/EU fits 3 blocks/CU (12 waves/CU),
// the TLP regime where the m97-class structure hits its ~900 TF ceiling
// (m114: implicit wave-overlap is what hides the barrier drain).
// ---------------------------------------------------------------------------
template <bool WF32, typename TC, bool BIAS>
__global__ __launch_bounds__(256, 3) void gemm_async(
    const bf16_t* __restrict__ A, int lda, const void* __restrict__ Wv,
    const float* __restrict__ bias, TC* __restrict__ C, int ldc,
    int M, int N, int K) {
  constexpr int BST = WF32 ? 40 : 32;
  __shared__ bf16_t As[2][128 * 32];   // unpadded: global_load_lds layout
  __shared__ bf16_t Bs[2][128 * BST];

  const int tid = threadIdx.x;
  const int i = tid & 63;
  const int w = tid >> 6;
  const int l16 = tid & 15;
  const int quad = (tid >> 4) & 3;
  const int wm = w & 1;
  const int wn = w >> 1;

  // T1: bijective XCD swizzle (requires nwg % 8 == 0; both grids satisfy)
  const int nwg = gridDim.x * gridDim.y;
  int wg = blockIdx.y * gridDim.x + blockIdx.x;
  if ((nwg & 7) == 0) wg = (wg & 7) * (nwg >> 3) + (wg >> 3);
  const int m0 = (wg / gridDim.x) * 128;
  const int n0 = (wg % gridDim.x) * 128;

  const bf16_t* ag = A + (size_t)(m0 + w * 32 + (i >> 2)) * lda + (i & 3) * 8;
  bf16_t* as0[2] = {&As[0][(w * 32) * 32], &As[1][(w * 32) * 32]};
  bf16_t* as1[2] = {&As[0][(w * 32 + 16) * 32], &As[1][(w * 32 + 16) * 32]};

  const bf16_t* bg = nullptr;
  bf16_t *bs0[2] = {nullptr, nullptr}, *bs1[2] = {nullptr, nullptr};
  const float* wfg = nullptr;
  bf16_t* bsw[2] = {nullptr, nullptr};
  if (!WF32) {
    bg = (const bf16_t*)Wv + (size_t)(n0 + w * 32 + (i >> 2)) * K + (i & 3) * 8;
    bs0[0] = &Bs[0][(w * 32) * 32];
    bs0[1] = &Bs[1][(w * 32) * 32];
    bs1[0] = &Bs[0][(w * 32 + 16) * 32];
    bs1[1] = &Bs[1][(w * 32 + 16) * 32];
  } else {
    const int srow = tid >> 1;
    const int scol = (tid & 1) * 16;
    wfg = (const float*)Wv + (size_t)(n0 + srow) * K + scol;
    bsw[0] = &Bs[0][srow * BST + scol];
    bsw[1] = &Bs[1][srow * BST + scol];
  }

  f32x4 acc[4][4] = {};

  // ---- prologue: stage K-tile 0 into buffer 0 ----
  gld16(ag, as0[0]);
  gld16(ag + 16 * lda, as1[0]);
  if (!WF32) {
    gld16(bg, bs0[0]);
    gld16(bg + 16 * K, bs1[0]);
  } else {
    f32x4 a = *(const f32x4*)(wfg);
    f32x4 b = *(const f32x4*)(wfg + 4);
    f32x4 c2 = *(const f32x4*)(wfg + 8);
    f32x4 d = *(const f32x4*)(wfg + 12);
    bf16x8 r0, r1;
#pragma unroll
    for (int e = 0; e < 4; ++e) {
      r0[e] = (bf16_t)a[e];
      r0[4 + e] = (bf16_t)b[e];
      r1[e] = (bf16_t)c2[e];
      r1[4 + e] = (bf16_t)d[e];
    }
    *(bf16x8*)(bsw[0]) = r0;
    *(bf16x8*)(bsw[0] + 8) = r1;
  }
  __syncthreads();  // implicit vmcnt(0): tile 0 resident

  int cur = 0;
  for (int k0 = 0; k0 < K; k0 += 32) {
    const bool has_next = (k0 + 32 < K);
    const int nxt = cur ^ 1;
    f32x4 wa, wb, wc, wd;  // WF32 staging regs (issued early, used late)

    // issue next tile's loads -> other buffer (in flight during compute)
    if (has_next) {
      gld16(ag + k0 + 32, as0[nxt]);
      gld16(ag + 16 * lda + k0 + 32, as1[nxt]);
      if (!WF32) {
        gld16(bg + k0 + 32, bs0[nxt]);
        gld16(bg + 16 * K + k0 + 32, bs1[nxt]);
      } else {
        wa = *(const f32x4*)(wfg + k0 + 32);
        wb = *(const f32x4*)(wfg + k0 + 36);
        wc = *(const f32x4*)(wfg + k0 + 40);
        wd = *(const f32x4*)(wfg + k0 + 44);
      }
    }

    // compute current tile
    bf16x8 af[4], bfr[4];
#pragma unroll
    for (int t = 0; t < 4; ++t) {
      af[t] = *(const bf16x8*)&As[cur][(wm * 64 + t * 16 + l16) * 32 + quad * 8];
      bfr[t] =
          *(const bf16x8*)&Bs[cur][(wn * 64 + t * 16 + l16) * BST + quad * 8];
    }
    __builtin_amdgcn_s_setprio(1);
#pragma unroll
    for (int mi = 0; mi < 4; ++mi)
#pragma unroll
      for (int ni = 0; ni < 4; ++ni)
        acc[mi][ni] = MFMA16(af[mi], bfr[ni], acc[mi][ni]);
    __builtin_amdgcn_s_setprio(0);

    // WF32: convert + commit staged regs (vmcnt waits here, after MFMA)
    if (WF32 && has_next) {
      bf16x8 r0, r1;
#pragma unroll
      for (int e = 0; e < 4; ++e) {
        r0[e] = (bf16_t)wa[e];
        r0[4 + e] = (bf16_t)wb[e];
        r1[e] = (bf16_t)wc[e];
        r1[4 + e] = (bf16_t)wd[e];
      }
      *(bf16x8*)(bsw[nxt]) = r0;
      *(bf16x8*)(bsw[nxt] + 8) = r1;
    }

    __syncthreads();  // drains vmcnt+lgkmcnt; next tile resident, cur free
    cur = nxt;
  }

#pragma unroll
  for (int ni = 0; ni < 4; ++ni) {
    const int col = n0 + wn * 64 + ni * 16 + l16;
    const float bv = BIAS ? bias[col] : 0.0f;
#pragma unroll
    for (int mi = 0; mi < 4; ++mi) {
      const int row = m0 + wm * 64 + mi * 16 + quad * 4;
#pragma unroll
      for (int r = 0; r < 4; ++r)
        C[(size_t)(row + r) * ldc + col] = (TC)(acc[mi][ni][r] + bv);
    }
  }
}

// ---------------------------------------------------------------------------
// Flash attention (causal), qkv interleaved [B*T, 3C] bf16 (q|k|v).
// Output overwrites the Q slot in place (R3-verified disjointness).
//
// Work-balanced: block p processes q-strips qt=p and qt=15-p -> every block
// does exactly 34 j-tiles. Grid (8, B*H) = 512 blocks of 512 threads.
//
// v2: swapped QK^T (S^T = mfma(K,Q)); lane holds a full q-row slice.
// v3: exp2-domain softmax; diagonal-only causal mask; exact defer-skip;
//     setprio around MFMA clusters.
// v4 (this round): double-buffered Ks/Vt -> ONE barrier per tile, order
//     [commit(j) -> sync -> issue loads(j+1) -> compute(j)].
//     Race audit: commit(j) into buf(j) vs compute(j-2) reads of buf(j) is
//     separated by iter j-1's barrier; commit(j) vs compute(j-1) touch
//     disjoint buffers; compute(j) sees commits via iter-j barrier (lgkm
//     drained by __syncthreads). Loads issued AFTER the barrier escape its
//     implicit vmcnt(0) drain -> consumed one tile later via reg dep (T14).
//     Strip-boundary __syncthreads protects the first commit of a strip.
// ---------------------------------------------------------------------------
__global__ __launch_bounds__(512, 4) void attn_mfma(bf16_t* __restrict__ qkv) {
  constexpr int T = 2048, C3 = 3072, C = 1024;
  __shared__ bf16_t Ks[2][64 * 72];   // [buf][token][d], +8 pad
  __shared__ bf16_t Vt[2][64 * 72];   // [buf][d][token], +8 pad
  __shared__ bf16_t Ps[8 * 16 * 72];  // per-wave P tile [qrow][key]

  const int tid = threadIdx.x;
  const int wave = tid >> 6;        // 0..7
  const int lane = tid & 63;
  const int l16 = tid & 15;
  const int quad = (tid >> 4) & 3;
  const int p = blockIdx.x;         // 0..7 -> strips p and 15-p
  const int b = blockIdx.y >> 4;
  const int h = blockIdx.y & 15;
  bf16_t* base = qkv + (size_t)b * T * C3;

  // 1/sqrt(64) * log2(e): softmax entirely in exp2 domain.
  const float QSCALE = 0.125f * 1.44269504088896340736f;

  // K staging map (waves 0-3): token = tid>>2 (0..63), 16 d's at (tid&3)*16
  const int kst = tid >> 2;
  const int ksd = (tid & 3) * 16;
  // V staging map (waves 4-7): token = lane, 16 d's at (wave-4)*16
  const int vtok = lane;
  const int vdg = (wave - 4) * 16;

  bf16_t* pw = &Ps[wave * 16 * 72];

  bf16x8 st0, st1;  // staging regs: K halves (waves 0-3) or V halves (4-7)

  for (int s = 0; s < 2; ++s) {
    const int qt = (s == 0) ? p : 15 - p;
    const int Q0 = qt * 128;
    const int qlo = Q0 + wave * 16;
    const int jmax = Q0 + 64;

    // Q fragments, prescaled by 0.125*log2e (one extra bf16 rounding on Q)
    bf16x8 qf[2];
    {
      const bf16_t* qp = base + (size_t)(qlo + l16) * C3 + h * 64 + quad * 8;
      bf16x8 a = *(const bf16x8*)qp;
      bf16x8 c = *(const bf16x8*)(qp + 32);
#pragma unroll
      for (int e = 0; e < 8; ++e) {
        a[e] = (bf16_t)((float)a[e] * QSCALE);
        c[e] = (bf16_t)((float)c[e] * QSCALE);
      }
      qf[0] = a;
      qf[1] = c;
    }

    f32x4 Of[4] = {};
    float mrow = -1e30f;
    float lrow = 0.f;

    // prologue: issue tile-0 loads into regs (T14 split)
    if (wave < 4) {
      const bf16_t* kp = base + (size_t)kst * C3 + C + h * 64 + ksd;
      st0 = *(const bf16x8*)kp;
      st1 = *(const bf16x8*)(kp + 8);
    } else {
      const bf16_t* vp = base + (size_t)vtok * C3 + 2 * C + h * 64 + vdg;
      st0 = *(const bf16x8*)vp;
      st1 = *(const bf16x8*)(vp + 8);
    }

    __syncthreads();  // strip boundary: prior readers of all LDS bufs done

    for (int j0 = 0; j0 <= jmax; j0 += 64) {
      const int buf = (j0 >> 6) & 1;
      // commit staged regs (tile j) -> LDS[buf]
      if (wave < 4) {
        *(bf16x8*)&Ks[buf][kst * 72 + ksd] = st0;
        *(bf16x8*)&Ks[buf][kst * 72 + ksd + 8] = st1;
      } else {
#pragma unroll
        for (int e = 0; e < 8; ++e) {
          Vt[buf][(vdg + e) * 72 + vtok] = st0[e];
          Vt[buf][(vdg + 8 + e) * 72 + vtok] = st1[e];
        }
      }
      __syncthreads();  // tile j visible; buf^1 free for next commit

      // issue next tile's loads AFTER the barrier (escapes vmcnt(0) drain);
      // consumed at iter j+1's commit via register dependency.
      if (j0 + 64 <= jmax) {
        const int jn = j0 + 64;
        if (wave < 4) {
          const bf16_t* kp = base + (size_t)(jn + kst) * C3 + C + h * 64 + ksd;
          st0 = *(const bf16x8*)kp;
          st1 = *(const bf16x8*)(kp + 8);
        } else {
          const bf16_t* vp =
              base + (size_t)(jn + vtok) * C3 + 2 * C + h * 64 + vdg;
          st0 = *(const bf16x8*)vp;
          st1 = *(const bf16x8*)(vp + 8);
        }
      }

      if (qlo + 15 < j0) continue;  // wave-uniform: fully-masked wave skips

      // S^T tile: lane holds S[qlo+l16][j0 + nt*16 + quad*4 + r]
      float Sv[4][4];
      const int qrow = qlo + l16;
      __builtin_amdgcn_s_setprio(1);
#pragma unroll
      for (int nt = 0; nt < 4; ++nt) {
        f32x4 sacc = {};
#pragma unroll
        for (int s2 = 0; s2 < 2; ++s2) {
          bf16x8 kf = *(const bf16x8*)&Ks[buf][(nt * 16 + l16) * 72 +
                                              s2 * 32 + quad * 8];
          sacc = MFMA16(kf, qf[s2], sacc);  // swapped: rows=keys, cols=qrows
        }
#pragma unroll
        for (int r = 0; r < 4; ++r) Sv[nt][r] = sacc[r];
      }
      __builtin_amdgcn_s_setprio(0);

      // causal mask: only the diagonal-overlap tile needs it (wave-uniform)
      if (j0 + 64 > qlo) {
#pragma unroll
        for (int nt = 0; nt < 4; ++nt) {
          const int keyb = j0 + nt * 16 + quad * 4;
#pragma unroll
          for (int r = 0; r < 4; ++r)
            if (keyb + r > qrow) Sv[nt][r] = -1e30f;
        }
      }

      // tile max for this lane's row (tree, then cross-quad)
      float vm[4];
#pragma unroll
      for (int nt = 0; nt < 4; ++nt)
        vm[nt] = fmaxf(fmaxf(Sv[nt][0], Sv[nt][1]),
                       fmaxf(Sv[nt][2], Sv[nt][3]));
      float v = fmaxf(fmaxf(vm[0], vm[1]), fmaxf(vm[2], vm[3]));
      v = fmaxf(v, __shfl_xor(v, 16));
      v = fmaxf(v, __shfl_xor(v, 32));

      // exact defer-skip: when no row grew, alpha==1 exactly -> skip rescale
      if (__any(v > mrow)) {
        const float mnew = fmaxf(mrow, v);
        const float alpha = __builtin_amdgcn_exp2f(mrow - mnew);
        mrow = mnew;
        lrow *= alpha;
        float ar[4];
#pragma unroll
        for (int r = 0; r < 4; ++r) ar[r] = __shfl(alpha, quad * 4 + r, 16);
#pragma unroll
        for (int dt = 0; dt < 4; ++dt)
#pragma unroll
          for (int r = 0; r < 4; ++r) Of[dt][r] *= ar[r];
      }

      // P = exp2(S - m); pack 4 consecutive keys -> one ds_write_b64 per nt
      float rsn[4];
#pragma unroll
      for (int nt = 0; nt < 4; ++nt) {
        bf16x4 pk;
        float r0 = __builtin_amdgcn_exp2f(Sv[nt][0] - mrow);
        float r1 = __builtin_amdgcn_exp2f(Sv[nt][1] - mrow);
        float r2 = __builtin_amdgcn_exp2f(Sv[nt][2] - mrow);
        float r3 = __builtin_amdgcn_exp2f(Sv[nt][3] - mrow);
        pk[0] = (bf16_t)r0;
        pk[1] = (bf16_t)r1;
        pk[2] = (bf16_t)r2;
        pk[3] = (bf16_t)r3;
        rsn[nt] = (r0 + r1) + (r2 + r3);
        *(bf16x4*)&pw[l16 * 72 + nt * 16 + quad * 4] = pk;
      }
      float rs = (rsn[0] + rsn[1]) + (rsn[2] + rsn[3]);
      rs += __shfl_xor(rs, 16);
      rs += __shfl_xor(rs, 32);
      lrow += rs;

      // PV: P A-frag read back (wave-private tile; no barrier needed)
      bf16x8 pf0 = *(const bf16x8*)&pw[l16 * 72 + quad * 8];
      bf16x8 pf1 = *(const bf16x8*)&pw[l16 * 72 + 32 + quad * 8];
      __builtin_amdgcn_s_setprio(1);
#pragma unroll
      for (int dt = 0; dt < 4; ++dt) {
        bf16x8 vf0 =
            *(const bf16x8*)&Vt[buf][(dt * 16 + l16) * 72 + quad * 8];
        bf16x8 vf1 =
            *(const bf16x8*)&Vt[buf][(dt * 16 + l16) * 72 + 32 + quad * 8];
        Of[dt] = MFMA16(pf0, vf0, Of[dt]);
        Of[dt] = MFMA16(pf1, vf1, Of[dt]);
      }
      __builtin_amdgcn_s_setprio(0);
    }

    // epilogue: broadcast l to row domain, write O over this wave's Q rows
    float lr[4];
#pragma unroll
    for (int r = 0; r < 4; ++r) lr[r] = __shfl(lrow, quad * 4 + r, 16);
    const int t = Q0 + wave * 16 + quad * 4;
#pragma unroll
    for (int r = 0; r < 4; ++r) {
      const float inv = 1.0f / lr[r];
      bf16_t* op = base + (size_t)(t + r) * C3 + h * 64 + l16;
#pragma unroll
      for (int dt = 0; dt < 4; ++dt)
        op[dt * 16] = (bf16_t)(Of[dt][r] * inv);
    }
  }
}

// ---------------------------------------------------------------------------
// I/O contract (R8 probe): ALL inputs f32; output f32.
// ---------------------------------------------------------------------------
extern "C" void kernel_launch(void* const* d_in, const int* in_sizes, int n_in,
                              void* d_out, int out_size, void* d_ws,
                              size_t ws_size, hipStream_t stream) {
  constexpr int B = 4, T = 2048, C = 1024;
  constexpr int M = B * T;  // 8192

  const float* x = (const float*)d_in[0];
  const float* w_qkv = (const float*)d_in[1];
  const float* w_out = (const float*)d_in[2];
  const float* b_out = (const float*)d_in[3];
  for (int i = 0; i < n_in; ++i) {
    const long long s = in_sizes[i];
    if (s == (long long)M * C) x = (const float*)d_in[i];
    else if (s == (long long)3 * C * C) w_qkv = (const float*)d_in[i];
    else if (s == (long long)C * C) w_out = (const float*)d_in[i];
    else if (s == C) b_out = (const float*)d_in[i];
  }

  // bf16 copies of x and w_qkv live in d_out (32 MB): dead before the final
  // GEMM overwrites d_out. ws holds qkv [M,3C] bf16 = 48 MB (proven safe);
  // if ws has 2 MB more, a bf16 copy of w_out lives after qkv so the final
  // GEMM can use the fast global_load_lds path instead of WF32 staging.
  bf16_t* xb = (bf16_t*)d_out;                    // 16 MB
  bf16_t* wqb = xb + (size_t)M * C;               // 6 MB
  bf16_t* qkv = (bf16_t*)d_ws;                    // 48 MB
  bf16_t* wob = qkv + (size_t)M * 3 * C;          // +2 MB (guarded)
  const bool ws_ok =
      ws_size >= (size_t)M * 3 * C * 2 + (size_t)C * C * 2;

  cvt_f32_bf16<<<1024, 256, 0, stream>>>(x, xb, (long long)M * C);
  cvt_f32_bf16<<<512, 256, 0, stream>>>(w_qkv, wqb, 3LL * C * C);
  if (ws_ok)
    cvt_f32_bf16<<<256, 256, 0, stream>>>(w_out, wob, (long long)C * C);

  // fused QKV: [M,3C] = xb @ wqb^T
  gemm_async<false, bf16_t, false>
      <<<dim3(3 * C / 128, M / 128), 256, 0, stream>>>(
          xb, C, wqb, nullptr, qkv, 3 * C, M, 3 * C, C);

  // attention in place (Q slot of qkv); work-balanced pairing grid
  attn_mfma<<<dim3(8, B * 16), 512, 0, stream>>>(qkv);

  // out = att @ w_out^T + b_out -> f32 d_out (overwrites xb/wqb, now dead)
  if (ws_ok)
    gemm_async<false, float, true><<<dim3(C / 128, M / 128), 256, 0, stream>>>(
        qkv, 3 * C, wob, b_out, (float*)d_out, C, M, C, C);
  else
    gemm_async<true, float, true><<<dim3(C / 128, M / 128), 256, 0, stream>>>(
        qkv, 3 * C, w_out, b_out, (float*)d_out, C, M, C, C);
}